// Round 2
// baseline (155.717 us; speedup 1.0000x reference)
//
#include <hip/hip_runtime.h>
#include <hip/hip_bf16.h>

#define DIMV 512
#define HDV 64

typedef __bf16 bf16x8_t __attribute__((ext_vector_type(8)));
typedef float f32x4_t __attribute__((ext_vector_type(4)));

union Frag {
  bf16x8_t v;
  unsigned short u[8];
  unsigned int w[4];
  uint2 d[2];
};

__device__ __forceinline__ unsigned short f2bf(float f) {
  return __builtin_bit_cast(unsigned short, (__bf16)f);
}
__device__ __forceinline__ float bf2f(unsigned int h) {
  return __builtin_bit_cast(float, h << 16);
}

// LDS layout (bytes):
//   K tiles : 2 x 8192  @ 0      rows 128 B (64 ch bf16), XOR-swizzled by ((row&7)<<4)
//   Vt tiles: 2 x 9216  @ 16384  rows 144 B (64 t bf16 + 8 pad)
//   LePE    : per-wave 2176 B chunks @ wave*2176 (reuses tile space after main loop)
#define KTILE_B 8192
#define VTILE_B 9216
#define VBASE   16384
#define SMEM_B  34816

__global__ __launch_bounds__(1024, 4)
void lepe_attn_kernel(const float* __restrict__ qkv,
                      const float* __restrict__ lw,
                      const float* __restrict__ lb,
                      float* __restrict__ out)
{
  __shared__ __align__(16) unsigned char smem[SMEM_B];

  const int head = blockIdx.x & 7;
  const int win  = blockIdx.x >> 3;
  const int bat  = win >> 3;
  const int nw   = win & 7;

  const int tid  = threadIdx.x;
  const int wave = tid >> 6;      // 0..15
  const int lane = tid & 63;
  const int l15  = lane & 15;
  const int g    = lane >> 4;

  const float* qptr = qkv;
  const float* kptr = qkv + 16777216;
  const float* vptr = qkv + 33554432;
  const int rowbase = bat * 4096;

  // window token -> float offset of its channel-slice start
  auto growf = [&](int tok) -> size_t {
    return ((size_t)(rowbase + ((tok >> 3) << 6) + (nw << 3) + (tok & 7))) * DIMV
           + head * HDV;
  };

  // ---- staging mapping: token st_t = wave*4+g (tile-local), channel quad st_c=l15
  const int st_t = (wave << 2) + g;
  const int st_c = l15;
  const float* kg = kptr + growf(st_t) + 4 * st_c;
  const float* vg = vptr + growf(st_t) + 4 * st_c;

  const int ksw = (st_t & 7) << 4;
  const int kwb = st_t * 128 + ((st_c * 8) ^ ksw);   // K write byte (in tile)
  const int vwb = (st_c * 4) * 144 + 2 * st_t;       // V^T write byte (d=st_c*4..+3)

  auto stage_write = [&](int buf, const float4& kv, const float4& vv) {
    unsigned char* kb = smem + buf * KTILE_B;
    uint2 kp;
    kp.x = (unsigned)f2bf(kv.x) | ((unsigned)f2bf(kv.y) << 16);
    kp.y = (unsigned)f2bf(kv.z) | ((unsigned)f2bf(kv.w) << 16);
    *(uint2*)(kb + kwb) = kp;
    unsigned char* vb = smem + VBASE + buf * VTILE_B;
    *(unsigned short*)(vb + vwb)       = f2bf(vv.x);
    *(unsigned short*)(vb + vwb + 144) = f2bf(vv.y);
    *(unsigned short*)(vb + vwb + 288) = f2bf(vv.z);
    *(unsigned short*)(vb + vwb + 432) = f2bf(vv.w);
  };

  // ---- prologue: issue tile-0 loads, then load Q fragments under that latency
  float4 kin = *(const float4*)kg;
  float4 vin = *(const float4*)vg;

  Frag qf[2][2];
  #pragma unroll
  for (int qi = 0; qi < 2; ++qi) {
    const float* qp = qptr + growf(wave * 32 + qi * 16 + l15);
    #pragma unroll
    for (int kc = 0; kc < 2; ++kc) {
      float4 f0 = *(const float4*)(qp + kc * 32 + 4 * g);
      float4 f1 = *(const float4*)(qp + kc * 32 + 4 * g + 16);
      qf[qi][kc].u[0] = f2bf(f0.x); qf[qi][kc].u[1] = f2bf(f0.y);
      qf[qi][kc].u[2] = f2bf(f0.z); qf[qi][kc].u[3] = f2bf(f0.w);
      qf[qi][kc].u[4] = f2bf(f1.x); qf[qi][kc].u[5] = f2bf(f1.y);
      qf[qi][kc].u[6] = f2bf(f1.z); qf[qi][kc].u[7] = f2bf(f1.w);
    }
  }

  stage_write(0, kin, vin);
  __syncthreads();

  const f32x4_t zero4 = {0.f, 0.f, 0.f, 0.f};
  f32x4_t ot[4][2];
  #pragma unroll
  for (int di = 0; di < 4; ++di)
    #pragma unroll
    for (int qi = 0; qi < 2; ++qi) ot[di][qi] = zero4;
  float lsum[2] = {0.f, 0.f};

  // ---- main loop: 8 key tiles of 64, double-buffered ----
  #pragma unroll 2
  for (int kt = 0; kt < 8; ++kt) {
    if (kt < 7) {  // issue next tile's loads first (latency hides under compute)
      kin = *(const float4*)(kg + (size_t)(kt + 1) * 262144);
      vin = *(const float4*)(vg + (size_t)(kt + 1) * 262144);
    }
    const unsigned char* kb = smem + (kt & 1) * KTILE_B;
    const unsigned char* vb = smem + VBASE + (kt & 1) * VTILE_B;

    #pragma unroll
    for (int hb = 0; hb < 2; ++hb) {   // half-tile: 32 keys
      Frag kf[2][2];
      #pragma unroll
      for (int kc = 0; kc < 2; ++kc)
        #pragma unroll
        for (int ki = 0; ki < 2; ++ki) {
          int row = hb * 32 + ki * 16 + l15;
          int sw = (row & 7) << 4;
          int cb = kc * 64 + 8 * g;
          const unsigned char* p = kb + row * 128;
          kf[kc][ki].d[0] = *(const uint2*)(p + (cb ^ sw));
          kf[kc][ki].d[1] = *(const uint2*)(p + ((cb + 32) ^ sw));
        }

      f32x4_t st[2][2];
      #pragma unroll
      for (int ki = 0; ki < 2; ++ki)
        #pragma unroll
        for (int qi = 0; qi < 2; ++qi) st[ki][qi] = zero4;

      #pragma unroll
      for (int kc = 0; kc < 2; ++kc)
        #pragma unroll
        for (int ki = 0; ki < 2; ++ki)
          #pragma unroll
          for (int qi = 0; qi < 2; ++qi)
            st[ki][qi] = __builtin_amdgcn_mfma_f32_16x16x32_bf16(
                kf[kc][ki].v, qf[qi][kc].v, st[ki][qi], 0, 0, 0);

      #pragma unroll
      for (int ki = 0; ki < 2; ++ki)
        #pragma unroll
        for (int qi = 0; qi < 2; ++qi) {
          f32x4_t s = st[ki][qi];
          #pragma unroll
          for (int r = 0; r < 4; ++r) {
            float p = __expf(s[r] * 0.125f);
            s[r] = p;
            lsum[qi] += p;
          }
          st[ki][qi] = s;
        }

      Frag vf[4];
      #pragma unroll
      for (int di = 0; di < 4; ++di) {
        int byte = (di * 16 + l15) * 144 + hb * 64 + 8 * g;
        vf[di].d[0] = *(const uint2*)(vb + byte);
        vf[di].d[1] = *(const uint2*)(vb + byte + 32);
      }

      #pragma unroll
      for (int qi = 0; qi < 2; ++qi) {
        Frag pb;
        #pragma unroll
        for (int r = 0; r < 4; ++r) {
          pb.u[r]     = f2bf(st[0][qi][r]);
          pb.u[4 + r] = f2bf(st[1][qi][r]);
        }
        #pragma unroll
        for (int di = 0; di < 4; ++di)
          ot[di][qi] = __builtin_amdgcn_mfma_f32_16x16x32_bf16(
              vf[di].v, pb.v, ot[di][qi], 0, 0, 0);
      }
    }

    if (kt < 7) stage_write((kt + 1) & 1, kin, vin);
    __syncthreads();
  }

  // ---- softmax denominators ----
  float rl[2];
  #pragma unroll
  for (int qi = 0; qi < 2; ++qi) {
    float s = lsum[qi];
    s += __shfl_xor(s, 16, 64);
    s += __shfl_xor(s, 32, 64);
    rl[qi] = 1.0f / s;
  }

  // ---- LePE (fp32 conv from global V, L2-hot) + epilogue ----
  // wave's tokens = wave*32..+31 = window rows yb..yb+3
  unsigned char* lep = smem + wave * 2176;   // [16 tok][68 ch] bf16, stride 136 B
  float wgt[9];
  {
    const float* wp = lw + (size_t)(head * HDV + lane) * 9;
    #pragma unroll
    for (int i = 0; i < 9; ++i) wgt[i] = wp[i];
  }
  const float bias = lb[head * HDV + lane];
  const int yb = wave * 4;

  float ra[8], rb2[8], rc2[8], rd[8];
  auto loadrow = [&](int y, float* dst) {
    if ((unsigned)y < 64u) {
      const float* p = vptr + ((size_t)(rowbase + y * 64 + nw * 8)) * DIMV
                       + head * HDV + lane;
      #pragma unroll
      for (int x = 0; x < 8; ++x) dst[x] = p[(size_t)x * DIMV];
    } else {
      #pragma unroll
      for (int x = 0; x < 8; ++x) dst[x] = 0.f;
    }
  };
  loadrow(yb - 1, ra);
  loadrow(yb,     rb2);
  loadrow(yb + 1, rc2);

  #pragma unroll
  for (int qi = 0; qi < 2; ++qi) {
    loadrow(yb + 2 * qi + 2, rd);
    // conv output rows yb+2qi (ra,rb2,rc2) and yb+2qi+1 (rb2,rc2,rd)
    #pragma unroll
    for (int x = 0; x < 8; ++x) {
      float a0 = bias, a1 = bias;
      if (x > 0) {
        a0 += ra[x-1]*wgt[0] + rb2[x-1]*wgt[3] + rc2[x-1]*wgt[6];
        a1 += rb2[x-1]*wgt[0] + rc2[x-1]*wgt[3] + rd[x-1]*wgt[6];
      }
      a0 += ra[x]*wgt[1] + rb2[x]*wgt[4] + rc2[x]*wgt[7];
      a1 += rb2[x]*wgt[1] + rc2[x]*wgt[4] + rd[x]*wgt[7];
      if (x < 7) {
        a0 += ra[x+1]*wgt[2] + rb2[x+1]*wgt[5] + rc2[x+1]*wgt[8];
        a1 += rb2[x+1]*wgt[2] + rc2[x+1]*wgt[5] + rd[x+1]*wgt[8];
      }
      *(unsigned short*)(lep + x * 136 + 2 * lane)       = f2bf(a0);
      *(unsigned short*)(lep + (8 + x) * 136 + 2 * lane) = f2bf(a1);
    }

    // epilogue for this qi chunk (reads this wave's just-written region)
    const float rlq = rl[qi];
    float* op = out + growf(wave * 32 + qi * 16 + l15);
    #pragma unroll
    for (int di = 0; di < 4; ++di) {
      uint2 lv = *(const uint2*)(lep + l15 * 136 + di * 32 + 8 * g);
      float4 o;
      o.x = ot[di][qi][0] * rlq + bf2f(lv.x & 0xffffu);
      o.y = ot[di][qi][1] * rlq + bf2f(lv.x >> 16);
      o.z = ot[di][qi][2] * rlq + bf2f(lv.y & 0xffffu);
      o.w = ot[di][qi][3] * rlq + bf2f(lv.y >> 16);
      *(float4*)(op + di * 16 + 4 * g) = o;
    }

    if (qi == 0) {  // roll rows for next chunk
      #pragma unroll
      for (int x = 0; x < 8; ++x) { ra[x] = rc2[x]; rb2[x] = rd[x]; }
      loadrow(yb + 3, rc2);
    }
  }
}

extern "C" void kernel_launch(void* const* d_in, const int* in_sizes, int n_in,
                              void* d_out, int out_size, void* d_ws, size_t ws_size,
                              hipStream_t stream) {
  const float* qkv = (const float*)d_in[0];
  const float* lw  = (const float*)d_in[1];
  const float* lb  = (const float*)d_in[2];
  float* out = (float*)d_out;
  (void)in_sizes; (void)n_in; (void)out_size; (void)d_ws; (void)ws_size;

  dim3 grid(512);    // 64 windows x 8 heads
  dim3 block(1024);  // 16 waves, 32 queries each
  hipLaunchKernelGGL(lepe_attn_kernel, grid, block, 0, stream, qkv, lw, lb, out);
}

// Round 3
// 97.357 us; speedup vs baseline: 1.5994x; 1.5994x over previous
//
#include <hip/hip_runtime.h>
#include <hip/hip_bf16.h>

#define DIMV 512
#define HDV  64
#define VSTR 514                       // shorts per Vt row (512 + 2 pad)
#define VT_BASE 8192
#define SMEM_B (VT_BASE + 64 * VSTR * 2)   // 73,984 B -> 2 blocks/CU

typedef __bf16 bf16x8_t __attribute__((ext_vector_type(8)));
typedef float f32x4_t __attribute__((ext_vector_type(4)));

union Frag { bf16x8_t v; unsigned short u[8]; unsigned int w[4]; uint2 d[2]; };

__device__ __forceinline__ unsigned short f2bf(float f) {
  return __builtin_bit_cast(unsigned short, (__bf16)f);
}
__device__ __forceinline__ float bf2f(unsigned int h) {
  return __builtin_bit_cast(float, h << 16);
}

__global__ __launch_bounds__(512, 4)
void lepe_attn_kernel(const float* __restrict__ qkv,
                      const float* __restrict__ lw,
                      const float* __restrict__ lb,
                      float* __restrict__ out)
{
  __shared__ __align__(16) unsigned char smem[SMEM_B];

  const int bidx = blockIdx.x;
  const int qh   = bidx & 1;          // query half (pairs adjacent -> L3 shares K/V)
  const int head = (bidx >> 1) & 7;
  const int win  = bidx >> 4;
  const int bat  = win >> 3;
  const int nw   = win & 7;

  const int tid  = threadIdx.x;
  const int wave = tid >> 6, lane = tid & 63;
  const int l15  = lane & 15, g = lane >> 4;

  const float* qptr = qkv;
  const float* kptr = qkv + 16777216;
  const float* vptr = qkv + 33554432;
  const int rowbase = bat * 4096;

  auto growf = [&](int tok) -> size_t {
    return ((size_t)(rowbase + ((tok >> 3) << 6) + (nw << 3) + (tok & 7))) * DIMV
           + head * HDV;
  };

  // staging mapping: token s_t (tile-local), channel quad s_c
  const int s_t = tid >> 4;           // 0..31
  const int s_c = (tid & 15) * 4;     // 0..60
  const size_t TSTRIDE = 131072;      // floats between 32-token groups

  const float* kg = kptr + growf(s_t) + s_c;
  const float* vg = vptr + growf(s_t) + s_c;
  const int kwb = s_t * 128 + ((s_c * 2) ^ ((s_t & 7) << 4));  // K tile write byte

  // prefetch K tile 0 while Vt stages
  float4 kpre = *(const float4*)kg;

  // ---- stage full-window V^T (resident), conflict-free writes ----
  unsigned short* vt = (unsigned short*)(smem + VT_BASE);
  #pragma unroll 4
  for (int j = 0; j < 16; ++j) {
    float4 f = *(const float4*)(vg + (size_t)j * TSTRIDE);
    int t = s_t + 32 * j;
    vt[(s_c + 0) * VSTR + t] = f2bf(f.x);
    vt[(s_c + 1) * VSTR + t] = f2bf(f.y);
    vt[(s_c + 2) * VSTR + t] = f2bf(f.z);
    vt[(s_c + 3) * VSTR + t] = f2bf(f.w);
  }

  // ---- Q frags, pre-scaled by 0.125*log2(e) so P = exp2(S) ----
  const float QSC = 0.1803368801f;
  const int qbase = qh * 256 + wave * 32;
  Frag qf[2][2];
  #pragma unroll
  for (int qi = 0; qi < 2; ++qi) {
    const float* qp = qptr + growf(qbase + qi * 16 + l15);
    #pragma unroll
    for (int kc = 0; kc < 2; ++kc) {
      float4 f0 = *(const float4*)(qp + kc * 32 + 4 * g);
      float4 f1 = *(const float4*)(qp + kc * 32 + 4 * g + 16);
      qf[qi][kc].u[0] = f2bf(f0.x * QSC); qf[qi][kc].u[1] = f2bf(f0.y * QSC);
      qf[qi][kc].u[2] = f2bf(f0.z * QSC); qf[qi][kc].u[3] = f2bf(f0.w * QSC);
      qf[qi][kc].u[4] = f2bf(f1.x * QSC); qf[qi][kc].u[5] = f2bf(f1.y * QSC);
      qf[qi][kc].u[6] = f2bf(f1.z * QSC); qf[qi][kc].u[7] = f2bf(f1.w * QSC);
    }
  }

  { // write K tile 0
    uint2 kp;
    kp.x = (unsigned)f2bf(kpre.x) | ((unsigned)f2bf(kpre.y) << 16);
    kp.y = (unsigned)f2bf(kpre.z) | ((unsigned)f2bf(kpre.w) << 16);
    *(uint2*)(smem + kwb) = kp;
  }
  __syncthreads();

  const f32x4_t zero4 = {0.f, 0.f, 0.f, 0.f};
  f32x4_t ot[4][2];
  #pragma unroll
  for (int di = 0; di < 4; ++di)
    #pragma unroll
    for (int qi = 0; qi < 2; ++qi) ot[di][qi] = zero4;
  float lsum[2] = {0.f, 0.f};

  // ---- main loop: 16 K-tiles of 32 keys, double-buffered ----
  #pragma unroll 2
  for (int kt = 0; kt < 16; ++kt) {
    if (kt < 15) kpre = *(const float4*)(kg + (size_t)(kt + 1) * TSTRIDE);

    const unsigned char* kb = smem + (kt & 1) * 4096;
    Frag kf[2][2];
    #pragma unroll
    for (int ki = 0; ki < 2; ++ki) {
      int r = ki * 16 + l15;
      int sw = (r & 7) << 4;
      const unsigned char* rowp = kb + r * 128;
      #pragma unroll
      for (int kc = 0; kc < 2; ++kc) {
        int cb = kc * 64 + g * 8;
        kf[ki][kc].d[0] = *(const uint2*)(rowp + (cb ^ sw));
        kf[ki][kc].d[1] = *(const uint2*)(rowp + ((cb + 32) ^ sw));
      }
    }

    f32x4_t st[2][2];
    #pragma unroll
    for (int ki = 0; ki < 2; ++ki)
      #pragma unroll
      for (int qi = 0; qi < 2; ++qi) st[ki][qi] = zero4;

    #pragma unroll
    for (int kc = 0; kc < 2; ++kc)
      #pragma unroll
      for (int ki = 0; ki < 2; ++ki)
        #pragma unroll
        for (int qi = 0; qi < 2; ++qi)
          st[ki][qi] = __builtin_amdgcn_mfma_f32_16x16x32_bf16(
              kf[ki][kc].v, qf[qi][kc].v, st[ki][qi], 0, 0, 0);

    #pragma unroll
    for (int ki = 0; ki < 2; ++ki)
      #pragma unroll
      for (int qi = 0; qi < 2; ++qi) {
        f32x4_t s = st[ki][qi];
        #pragma unroll
        for (int r = 0; r < 4; ++r) {
          float p = exp2f(s[r]);
          s[r] = p;
          lsum[qi] += p;
        }
        st[ki][qi] = s;
      }

    Frag vf[4];
    #pragma unroll
    for (int di = 0; di < 4; ++di) {
      const unsigned char* p = smem + VT_BASE + (di * 16 + l15) * (VSTR * 2)
                               + kt * 64 + 8 * g;
      vf[di].w[0] = *(const unsigned*)(p);
      vf[di].w[1] = *(const unsigned*)(p + 4);
      vf[di].w[2] = *(const unsigned*)(p + 32);
      vf[di].w[3] = *(const unsigned*)(p + 36);
    }

    #pragma unroll
    for (int qi = 0; qi < 2; ++qi) {
      Frag pb;
      #pragma unroll
      for (int r = 0; r < 4; ++r) {
        pb.u[r]     = f2bf(st[0][qi][r]);
        pb.u[4 + r] = f2bf(st[1][qi][r]);
      }
      #pragma unroll
      for (int di = 0; di < 4; ++di)
        ot[di][qi] = __builtin_amdgcn_mfma_f32_16x16x32_bf16(
            vf[di].v, pb.v, ot[di][qi], 0, 0, 0);
    }

    if (kt < 15) {  // write next K tile as late as possible (max vmcnt slack)
      uint2 kp;
      kp.x = (unsigned)f2bf(kpre.x) | ((unsigned)f2bf(kpre.y) << 16);
      kp.y = (unsigned)f2bf(kpre.z) | ((unsigned)f2bf(kpre.w) << 16);
      *(uint2*)(smem + ((kt + 1) & 1) * 4096 + kwb) = kp;
    }
    __syncthreads();
  }

  // ---- softmax denominators ----
  float rl[2];
  #pragma unroll
  for (int qi = 0; qi < 2; ++qi) {
    float s = lsum[qi];
    s += __shfl_xor(s, 16, 64);
    s += __shfl_xor(s, 32, 64);
    rl[qi] = 1.0f / s;
  }

  // ---- LePE conv from Vt LDS (lane = channel), results to registers ----
  float wgt[9];
  {
    const float* wp = lw + (size_t)(head * HDV + lane) * 9;
    #pragma unroll
    for (int i = 0; i < 9; ++i) wgt[i] = wp[i];
  }
  const float bias = lb[head * HDV + lane];
  const int yb = qh * 32 + wave * 4;

  float rm[8], rc[8], rp2[8], lout[32];
  auto loadrow = [&](int y, float* dst) {
    if ((unsigned)y < 64u) {
      const unsigned char* p = smem + VT_BASE + lane * (VSTR * 2) + y * 16;
      unsigned a0 = *(const unsigned*)(p);
      unsigned a1 = *(const unsigned*)(p + 4);
      unsigned a2 = *(const unsigned*)(p + 8);
      unsigned a3 = *(const unsigned*)(p + 12);
      dst[0] = bf2f(a0 & 0xffffu); dst[1] = bf2f(a0 >> 16);
      dst[2] = bf2f(a1 & 0xffffu); dst[3] = bf2f(a1 >> 16);
      dst[4] = bf2f(a2 & 0xffffu); dst[5] = bf2f(a2 >> 16);
      dst[6] = bf2f(a3 & 0xffffu); dst[7] = bf2f(a3 >> 16);
    } else {
      #pragma unroll
      for (int x = 0; x < 8; ++x) dst[x] = 0.f;
    }
  };
  loadrow(yb - 1, rm);
  loadrow(yb, rc);
  #pragma unroll
  for (int yy = 0; yy < 4; ++yy) {
    loadrow(yb + yy + 1, rp2);
    #pragma unroll
    for (int x = 0; x < 8; ++x) {
      float acc = bias;
      if (x > 0) acc += rm[x-1]*wgt[0] + rc[x-1]*wgt[3] + rp2[x-1]*wgt[6];
      acc += rm[x]*wgt[1] + rc[x]*wgt[4] + rp2[x]*wgt[7];
      if (x < 7) acc += rm[x+1]*wgt[2] + rc[x+1]*wgt[5] + rp2[x+1]*wgt[8];
      lout[yy * 8 + x] = acc;
    }
    #pragma unroll
    for (int x = 0; x < 8; ++x) { rm[x] = rc[x]; rc[x] = rp2[x]; }
  }

  __syncthreads();   // everyone done reading Vt; reuse LDS for transpose bounce

  unsigned char* bp = smem + wave * 4352;   // [32 tok][68 ch] bf16 per wave
  #pragma unroll
  for (int t = 0; t < 32; ++t)
    *(unsigned short*)(bp + t * 136 + 2 * lane) = f2bf(lout[t]);
  __syncthreads();

  // ---- normalize, add LePE, store ----
  #pragma unroll
  for (int qi = 0; qi < 2; ++qi) {
    const float rlq = rl[qi];
    const int tl = qi * 16 + l15;
    float* op = out + growf(qbase + tl);
    #pragma unroll
    for (int di = 0; di < 4; ++di) {
      uint2 lv = *(const uint2*)(bp + tl * 136 + di * 32 + 8 * g);
      float4 o;
      o.x = ot[di][qi][0] * rlq + bf2f(lv.x & 0xffffu);
      o.y = ot[di][qi][1] * rlq + bf2f(lv.x >> 16);
      o.z = ot[di][qi][2] * rlq + bf2f(lv.y & 0xffffu);
      o.w = ot[di][qi][3] * rlq + bf2f(lv.y >> 16);
      *(float4*)(op + di * 16 + 4 * g) = o;
    }
  }
}

extern "C" void kernel_launch(void* const* d_in, const int* in_sizes, int n_in,
                              void* d_out, int out_size, void* d_ws, size_t ws_size,
                              hipStream_t stream) {
  const float* qkv = (const float*)d_in[0];
  const float* lw  = (const float*)d_in[1];
  const float* lb  = (const float*)d_in[2];
  float* out = (float*)d_out;
  (void)in_sizes; (void)n_in; (void)out_size; (void)d_ws; (void)ws_size;

  dim3 grid(1024);   // 64 win x 8 heads x 2 query-halves
  dim3 block(512);   // 8 waves x 32 queries
  hipLaunchKernelGGL(lepe_attn_kernel, grid, block, 0, stream, qkv, lw, lb, out);
}